// Round 2
// baseline (213.701 us; speedup 1.0000x reference)
//
#include <hip/hip_runtime.h>
#include <hip/hip_bf16.h>
#include <stdint.h>

namespace {
constexpr int kBatch = 256;
constexpr int kNoise = 128;
constexpr int kIn    = 512;
constexpr int kOut   = 512;
constexpr int kXCols = kNoise + kIn;        // 640
constexpr int kPCols = kIn * kOut + kOut;   // 262656 (W row stride)
constexpr int kOTile = 32;
constexpr int kITile = 16;
constexpr int kSplits = kIn / kITile;       // 32 partial slabs
constexpr int kWStride = 68;                // LDS col stride in dwords (64 kp + 4 pad)
constexpr int kFeatsStride = 260;
constexpr int kSlab = kBatch * kOut + 64;   // partial slab stride, +256B to break
                                            // 512KB power-of-2 channel aliasing
}

typedef __bf16 bf16x8 __attribute__((ext_vector_type(8)));
typedef float  f32x4  __attribute__((ext_vector_type(4)));
typedef unsigned int u32x4 __attribute__((ext_vector_type(4)));

__device__ inline unsigned int pack_bf16x2(float lo, float hi) {
    unsigned int a = (unsigned int)__builtin_bit_cast(unsigned short, (__bf16)lo);
    unsigned int b = (unsigned int)__builtin_bit_cast(unsigned short, (__bf16)hi);
    return a | (b << 16);
}

// Barrier draining LDS ops only (lgkmcnt(0)); vmcnt untouched so global
// prefetch loads stay in flight across it.
__device__ inline void wg_barrier_lds() {
    __asm__ volatile("" ::: "memory");
    __builtin_amdgcn_s_waitcnt(0xC07F);   // lgkmcnt(0), vmcnt/expcnt = no-wait
    __builtin_amdgcn_s_barrier();
    __asm__ volatile("" ::: "memory");
}

// Stage 1: part[split][b][o] = sum_{i in split} feats[b,i]*(noise@W + bvec)[b, i*512+o]
//          (+ bias-term pass folded into split 0)
// Grid (16 o-tiles, 32 i-splits) = 512 WGs x 512 thr (8 waves), 2 WG/CU.
// Pipeline (phase-shifted dbuf): at iteration ip the wave passes the barrier,
// then STAGES tile[ip+1] (pack + one conflict-free ds_write_b128) and computes
// tile[ip] — the tile-write latency hides under the MFMAs instead of sitting
// between the write and the barrier.  Staging role: thread owns 4 consecutive
// kp (rows 8sw..8sw+7) of ONE column -> 8 scalar row loads (each instr still
// covers 2x128B coalesced segments across the wave) -> 1 ds_write_b128 whose
// start banks are uniformly spread (8 lanes per 4-bank group, optimal).
__global__ __launch_bounds__(512, 4)
void hyper_gemm_kernel(const float* __restrict__ x,
                       const float* __restrict__ W,
                       const float* __restrict__ bvec,
                       float* __restrict__ part)
{
    const int tid  = threadIdx.x;
    const int lane = tid & 63;
    const int wave = tid >> 6;     // 0..7, owns batch rows [wave*32, wave*32+32)
    const int q    = lane >> 4;
    const int l16  = lane & 15;

    const int o0 = blockIdx.x * kOTile;
    const int i0 = blockIdx.y * kITile;

    // W staging role: thread covers rows {8sw..8sw+7} (kp = 4sw..4sw+3), col sc
    const int sw = tid >> 5;            // 0..15 (kp quad)
    const int sc = tid & 31;            // 0..31 (col)

    __shared__ unsigned int wtile[2][kOTile * kWStride];   // dbuf bf16-pair tile [col][kp]
    __shared__ float feats_lds[kITile * kFeatsStride];     // [i][b] transposed
    __shared__ float bv_lds[(kITile + 1) * kOTile];        // [pass][col]

    const int nPass = (blockIdx.y == 0) ? (kITile + 1) : kITile;

    auto pass_cbase = [&](int p) -> size_t {
        return (p == kITile) ? (size_t)(kIn * kOut) : (size_t)(i0 + p) * kOut;
    };
    const float* wbase = W + (size_t)(8 * sw) * kPCols + o0 + sc;
    auto loadpass = [&](int p, float* r) {
        const float* wp = wbase + pass_cbase(p);
        #pragma unroll
        for (int rr = 0; rr < 8; ++rr) r[rr] = wp[(size_t)rr * kPCols];
    };

    // ---- prologue: issue depth-4 W prefetch FIRST (HBM-latency loads) ----
    float r0[8], rA[8], rB[8], rC[8];   // passes 0..3
    loadpass(0, r0);
    loadpass(1, rA);
    loadpass(2, rB);
    loadpass(3, rC);

    // bvec -> LDS
    for (int idx = tid; idx < (kITile + 1) * kOTile; idx += 512) {
        const int p = idx >> 5, c = idx & 31;
        const size_t cb = (p == kITile) ? (size_t)(kIn * kOut) : (size_t)(i0 + p) * kOut;
        bv_lds[idx] = bvec[cb + o0 + c];
    }

    // feats[b][i0+i] -> feats_lds[i][b]
    {
        const int i    = tid & 15;
        const int brow = tid >> 4;      // 0..31
        #pragma unroll
        for (int rep = 0; rep < 8; ++rep) {
            const int b = brow + rep * 32;
            feats_lds[i * kFeatsStride + b] = x[b * kXCols + kNoise + i0 + i];
        }
    }

    // Noise A-fragments (resident, 32 VGPRs). A[m=lane&15][k=q*8+j], k_global=32*s+s.
    bf16x8 afrag[2][4];
    #pragma unroll
    for (int rt = 0; rt < 2; ++rt) {
        const float* xr = x + (size_t)(wave * 32 + rt * 16 + l16) * kXCols;
        #pragma unroll
        for (int s = 0; s < 4; ++s) {
            const float* p = xr + s * 32 + q * 8;
            f32x4 u0 = *(const f32x4*)(p);
            f32x4 u1 = *(const f32x4*)(p + 4);
            bf16x8 a;
            a[0] = (__bf16)u0[0]; a[1] = (__bf16)u0[1];
            a[2] = (__bf16)u0[2]; a[3] = (__bf16)u0[3];
            a[4] = (__bf16)u1[0]; a[5] = (__bf16)u1[1];
            a[6] = (__bf16)u1[2]; a[7] = (__bf16)u1[3];
            afrag[rt][s] = a;
        }
    }

    // pack pass 0 -> tile 0 (single conflict-free b128 write per thread)
    {
        u32x4 pk;
        #pragma unroll
        for (int j = 0; j < 4; ++j) pk[j] = pack_bf16x2(r0[2 * j], r0[2 * j + 1]);
        *(u32x4*)&wtile[0][sc * kWStride + 4 * sw] = pk;
    }

    float oacc[2][2][4];   // [rt][nt][r]; b = wave*32+rt*16+q*4+r, o = o0+nt*16+l16
    #pragma unroll
    for (int rt = 0; rt < 2; ++rt)
        #pragma unroll
        for (int nt = 0; nt < 2; ++nt)
            #pragma unroll
            for (int r = 0; r < 4; ++r) oacc[rt][nt][r] = 0.f;

    // ---- pipelined i-loop: 1 barrier/pass; loop-top invariant:
    //      rA/rB/rC hold passes ip+1 / ip+2 / ip+3; tile[ip&1] fully written ----
    for (int ip = 0; ip < nPass; ++ip) {
        wg_barrier_lds();   // tile[ip&1] visible; everyone's reads of tile[(ip+1)&1] done

        // stage NEXT pass's tile (overlaps with this pass's MFMAs below)
        if (ip + 1 < nPass) {
            u32x4 pk;
            #pragma unroll
            for (int j = 0; j < 4; ++j) pk[j] = pack_bf16x2(rA[2 * j], rA[2 * j + 1]);
            *(u32x4*)&wtile[(ip + 1) & 1][sc * kWStride + 4 * sw] = pk;
        }
        // shift pipeline; issue pass ip+4 loads (consumed 3 iterations later)
        #pragma unroll
        for (int rr = 0; rr < 8; ++rr) { rA[rr] = rB[rr]; rB[rr] = rC[rr]; }
        if (ip + 4 < nPass) loadpass(ip + 4, rC);

        // GEMM: acc[b,col] = noise @ W[:, cbase+o0+col], from tile[ip&1]
        const unsigned int* wt = &wtile[ip & 1][0];
        f32x4 acc[2][2];
        const f32x4 zero = {0.f, 0.f, 0.f, 0.f};
        acc[0][0] = zero; acc[0][1] = zero; acc[1][0] = zero; acc[1][1] = zero;

        #pragma unroll
        for (int s = 0; s < 4; ++s) {
            #pragma unroll
            for (int nt = 0; nt < 2; ++nt) {
                // B layout [k=q*8+j][col=l16]: 4 consecutive uints = 8 bf16 (k asc)
                u32x4 raw = *(const u32x4*)&wt[(nt * 16 + l16) * kWStride + s * 16 + q * 4];
                bf16x8 bfrag = __builtin_bit_cast(bf16x8, raw);
                acc[0][nt] = __builtin_amdgcn_mfma_f32_16x16x32_bf16(
                    afrag[0][s], bfrag, acc[0][nt], 0, 0, 0);
                acc[1][nt] = __builtin_amdgcn_mfma_f32_16x16x32_bf16(
                    afrag[1][s], bfrag, acc[1][nt], 0, 0, 0);
            }
        }

        // epilogue (fp32): oacc += feats[b,i] * (acc + bvec[c]); bias pass scale=1
        const float bv0 = bv_lds[ip * kOTile + l16];
        const float bv1 = bv_lds[ip * kOTile + 16 + l16];

        if (ip < kITile) {
            // C/D layout: col = lane&15, row = q*4 + reg
            #pragma unroll
            for (int rt = 0; rt < 2; ++rt) {
                const f32x4 f4 = *(const f32x4*)&feats_lds[ip * kFeatsStride
                                        + wave * 32 + rt * 16 + q * 4];
                #pragma unroll
                for (int r = 0; r < 4; ++r) {
                    oacc[rt][0][r] += f4[r] * (acc[rt][0][r] + bv0);
                    oacc[rt][1][r] += f4[r] * (acc[rt][1][r] + bv1);
                }
            }
        } else {
            #pragma unroll
            for (int rt = 0; rt < 2; ++rt)
                #pragma unroll
                for (int r = 0; r < 4; ++r) {
                    oacc[rt][0][r] += acc[rt][0][r] + bv0;
                    oacc[rt][1][r] += acc[rt][1][r] + bv1;
                }
        }
    }

    // ---- stream partials (no atomics) ----
    float* pp = part + (size_t)blockIdx.y * kSlab;
    #pragma unroll
    for (int rt = 0; rt < 2; ++rt)
        #pragma unroll
        for (int nt = 0; nt < 2; ++nt) {
            const int o = o0 + nt * 16 + l16;
            #pragma unroll
            for (int r = 0; r < 4; ++r) {
                const int b = wave * 32 + rt * 16 + q * 4 + r;
                pp[(size_t)b * kOut + o] = oacc[rt][nt][r];
            }
        }
}

// Stage 2: out = sum over 32 slabs. 256 WGs x 128 thr; two independent
// accumulator chains so the 32 loads batch deep (latency-bound otherwise).
__global__ __launch_bounds__(128)
void reduce_kernel(const float* __restrict__ part, float* __restrict__ out)
{
    const size_t idx4 = ((size_t)blockIdx.x * 128 + threadIdx.x) * 4;
    f32x4 a0 = {0.f, 0.f, 0.f, 0.f};
    f32x4 a1 = {0.f, 0.f, 0.f, 0.f};
    #pragma unroll
    for (int s = 0; s < kSplits; s += 2) {
        a0 += *(const f32x4*)(part + (size_t)s * kSlab + idx4);
        a1 += *(const f32x4*)(part + (size_t)(s + 1) * kSlab + idx4);
    }
    *(f32x4*)(out + idx4) = a0 + a1;
}

extern "C" void kernel_launch(void* const* d_in, const int* in_sizes, int n_in,
                              void* d_out, int out_size, void* d_ws, size_t ws_size,
                              hipStream_t stream) {
    const float* x  = (const float*)d_in[0];
    const float* W  = (const float*)d_in[1];
    const float* bv = (const float*)d_in[2];
    float* out  = (float*)d_out;
    float* part = (float*)d_ws;   // 32 * kSlab * 4 B = 16.8 MB

    dim3 grid(kOut / kOTile, kSplits);  // (16, 32) = 512 WGs of 512 threads
    hyper_gemm_kernel<<<grid, 512, 0, stream>>>(x, W, bv, part);

    const int n4 = kBatch * kOut / 4;   // 32768 f32x4 outputs
    reduce_kernel<<<n4 / 128, 128, 0, stream>>>(part, out);
}